// Round 6
// baseline (430.787 us; speedup 1.0000x reference)
//
#include <hip/hip_runtime.h>
#include <hip/hip_bf16.h>
#include <math.h>

// PhiMoE sparse MoE block. E=8, H=1024, F=2048, T=1024.
// Inputs  (float32): hidden_states [1,1024,1024], gate_w [8,1024],
//   w1 [8,2048,1024], w2 [8,1024,2048], w3 [8,2048,1024]
// Outputs (float32, concat): final [1,1024,1024], router_logits [1024,8]
// R6: deep-pipelined weight stream via global_load_lds (T3+T4).
// Reg-prefetch rounds (R3-R5) capped at ~1 TB/s by Little's law: <=2KB
// outstanding vmem per CU vs ~10B/cy x ~700cy needed. global_load_lds
// decouples in-flight bytes from VGPRs: ring-4 LDS, 2 tiles (32KB) in
// flight, counted vmcnt (never 0 in loop), raw s_barrier.
// B tiles stored FRAGMENT-MAJOR via per-lane gathered DMA source: frag
// read = base + lane*16 -> conflict-free, no swizzle. f32->bf16 at read.
// Separate __shared__ array per ring slot + static ring indices so alias
// analysis can't inject cross-ring waits. A direct global->reg, depth-2.

#define T_TOK 1024
#define H_DIM 1024
#define F_DIM 2048
#define N_EXP 8
#define JIT 0.01f

#define BK  32
#define NK1 (H_DIM / BK)   // 32
#define NK2 (F_DIM / BK)   // 64
#define MT_MAX 24          // sum_e ceil(cnt_e/128) <= 24

typedef __bf16 bf16_t;
typedef __bf16 bf16x8 __attribute__((ext_vector_type(8)));
typedef float f32x4 __attribute__((ext_vector_type(4)));

__device__ inline bf16x8 cvt8(float4 a, float4 b) {
    bf16x8 r;
    r[0] = (bf16_t)a.x; r[1] = (bf16_t)a.y; r[2] = (bf16_t)a.z; r[3] = (bf16_t)a.w;
    r[4] = (bf16_t)b.x; r[5] = (bf16_t)b.y; r[6] = (bf16_t)b.z; r[7] = (bf16_t)b.w;
    return r;
}

__device__ inline void gl16(const float* g, float* l) {
    __builtin_amdgcn_global_load_lds(
        (const __attribute__((address_space(1))) unsigned int*)g,
        (__attribute__((address_space(3))) unsigned int*)l, 16, 0, 0);
}

// workspace layout (bytes)
#define WS_CNT   0
#define WS_BASE  64
#define WS_TOK   128
#define WS_WGT   (128 + 32768)
#define WS_SLOT  (WS_WGT + 32768)
#define WS_INTER 131072              // bf16 [2048][2048] compacted intermediate (8 MB)
#define WS_ACC   (131072 + 8388608)  // f32  [2][1024][1024] slot accumulators (8 MB)

// ---------------- Router: logits + sparsemixer top-2 ----------------
__global__ __launch_bounds__(256) void router_k(
    const float* __restrict__ x, const float* __restrict__ gw,
    float* __restrict__ logits_out,
    int* __restrict__ cnt, int* __restrict__ tok,
    float* __restrict__ wgt, int* __restrict__ slot)
{
    int wave = threadIdx.x >> 6, lane = threadIdx.x & 63;
    int t = blockIdx.x * 4 + wave;
    const float* xr = x + (size_t)t * H_DIM;
    int h0 = lane * 16;

    float acc[N_EXP];
#pragma unroll
    for (int e = 0; e < N_EXP; e++) acc[e] = 0.f;
#pragma unroll
    for (int j = 0; j < 16; j += 4) {
        float4 xv = *(const float4*)(xr + h0 + j);
#pragma unroll
        for (int e = 0; e < N_EXP; e++) {
            float4 gv = *(const float4*)(gw + e * H_DIM + h0 + j);
            acc[e] += xv.x * gv.x + xv.y * gv.y + xv.z * gv.z + xv.w * gv.w;
        }
    }
#pragma unroll
    for (int m = 32; m > 0; m >>= 1)
#pragma unroll
        for (int e = 0; e < N_EXP; e++) acc[e] += __shfl_xor(acc[e], m, 64);

    if (lane == 0) {
        float s[N_EXP];
#pragma unroll
        for (int e = 0; e < N_EXP; e++) {
            s[e] = acc[e];
            logits_out[t * N_EXP + e] = s[e];
        }
        float max1 = -INFINITY; int sel1 = 0;
        for (int e = 0; e < N_EXP; e++) if (s[e] > max1) { max1 = s[e]; sel1 = e; }
        float denom1 = 0.f;
        for (int e = 0; e < N_EXP; e++) {
            float factor = fmaxf(fabsf(s[e]), max1);
            bool m = ((max1 - s[e]) / factor) > (2.0f * JIT);
            if (!m) denom1 += expf(s[e] - max1);
        }
        float mult1 = 1.0f / denom1;
        float max2 = -INFINITY; int sel2 = 0;
        for (int e = 0; e < N_EXP; e++)
            if (e != sel1 && s[e] > max2) { max2 = s[e]; sel2 = e; }
        float denom2 = 0.f;
        for (int e = 0; e < N_EXP; e++) {
            if (e == sel1) continue;
            float factor = fmaxf(fabsf(s[e]), max2);
            bool m = ((max2 - s[e]) / factor) > (2.0f * JIT);
            if (!m) denom2 += expf(s[e] - max2);
        }
        float mult2 = 1.0f / denom2;

        int p1 = atomicAdd(&cnt[sel1], 1);
        tok[sel1 * T_TOK + p1] = t; wgt[sel1 * T_TOK + p1] = mult1; slot[sel1 * T_TOK + p1] = 0;
        int p2 = atomicAdd(&cnt[sel2], 1);
        tok[sel2 * T_TOK + p2] = t; wgt[sel2 * T_TOK + p2] = mult2; slot[sel2 * T_TOK + p2] = 1;
    }
}

__global__ void prefix_k(const int* __restrict__ cnt, int* __restrict__ base)
{
    if (threadIdx.x == 0 && blockIdx.x == 0) {
        int a = 0;
        for (int e = 0; e < N_EXP; e++) { base[e] = a; a += cnt[e]; }
    }
}

// ---------------- GEMM1: inter = silu(x@w1^T) * (x@w3^T) ----------------
// Block 128 rows x 64 cols (both mats), BK=32, 256 thr / 4 waves (2x2).
// B via global_load_lds into fragment-major f32 ring-4 LDS (16KB tiles);
// A direct per-lane global->reg depth-2. Counted vmcnt 16/12/0.
__global__ __launch_bounds__(256, 2) void gemm1_k(
    const float* __restrict__ x,
    const float* __restrict__ w1,
    const float* __restrict__ w3,
    const int* __restrict__ cnt, const int* __restrict__ base,
    const int* __restrict__ tok,
    bf16_t* __restrict__ inter)
{
    int mt = blockIdx.x >> 5;       // flat 128-row chunk across experts
    int nt = blockIdx.x & 31;       // 32 n-tiles of 64
    int e = 0, m0 = 0, found = 0, accb = 0;
#pragma unroll
    for (int ee = 0; ee < N_EXP; ee++) {
        int b = (cnt[ee] + 127) >> 7;
        if (!found && mt < accb + b) { e = ee; m0 = (mt - accb) << 7; found = 1; }
        accb += b;
    }
    if (!found) return;
    int cntE = cnt[e];
    int n0 = nt * 64;
    int tid = threadIdx.x;
    int lane = tid & 63, quad = lane >> 4, l16 = lane & 15;
    int wave = tid >> 6;
    int wm = wave >> 1, wn = wave & 1;   // 2x2 wave grid: 64 rows x 32 cols each

    // ring of 4 SEPARATE tiles (16KB each: [mat2][fj4][h2][lane64] x 16B)
    __shared__ __align__(16) float Bl0[4096];
    __shared__ __align__(16) float Bl1[4096];
    __shared__ __align__(16) float Bl2[4096];
    __shared__ __align__(16) float Bl3[4096];
    __shared__ int tokL[128];

    if (tid < 128) {
        int r = m0 + tid;
        tokL[tid] = tok[e * T_TOK + (r < cntE ? r : cntE - 1)];
    }
    __syncthreads();

    const float* w1e = w1 + (size_t)e * F_DIM * H_DIM;
    const float* w3e = w3 + (size_t)e * F_DIM * H_DIM;

    // B DMA groups: g = wave*4+j; mat=g>>3, fj=(g>>1)&3, h=g&1.
    // group (mat,fj,h) lane l holds w[n0+fj*16+(l&15)][kk*32+(l>>4)*8+h*4 ..+4]
    const float* srcB[4];
    int dstF[4];
#pragma unroll
    for (int j = 0; j < 4; j++) {
        int g = wave * 4 + j;
        int mat = g >> 3, fj = (g >> 1) & 3, h = g & 1;
        srcB[j] = (mat ? w3e : w1e) + (size_t)(n0 + fj * 16 + l16) * H_DIM + quad * 8 + h * 4;
        dstF[j] = mat * 2048 + fj * 512 + h * 256;   // floats; +lane*16B by HW
    }

    // A: per-lane direct rows (wave rows wm*64 + fi*16 + l16), k = quad*8..+8
    int aoff[4];
#pragma unroll
    for (int fi = 0; fi < 4; fi++)
        aoff[fi] = tokL[wm * 64 + fi * 16 + l16] * H_DIM + quad * 8;

    f32x4 acc1[4][2], acc3[4][2];
#pragma unroll
    for (int fi = 0; fi < 4; fi++)
#pragma unroll
        for (int fj = 0; fj < 2; fj++) {
            acc1[fi][fj] = f32x4{0.f, 0.f, 0.f, 0.f};
            acc3[fi][fj] = f32x4{0.f, 0.f, 0.f, 0.f};
        }

    float4 pa[2][4][2];   // [parity][fi][half]

#define G1_ISSUE_B(T, WR)                                                   \
    { _Pragma("unroll") for (int j = 0; j < 4; j++)                         \
          gl16(srcB[j] + (T) * 32, WR + dstF[j]); }

#define G1_ISSUE_A(T, PAR)                                                  \
    { _Pragma("unroll") for (int fi = 0; fi < 4; fi++) {                    \
          pa[PAR][fi][0] = *(const float4*)(x + aoff[fi] + (T) * 32);       \
          pa[PAR][fi][1] = *(const float4*)(x + aoff[fi] + (T) * 32 + 4); } }

#define G1_SYNC(N)                                                          \
    __builtin_amdgcn_sched_barrier(0);                                      \
    asm volatile("s_waitcnt vmcnt(" #N ")" ::: "memory");                   \
    __builtin_amdgcn_s_barrier();                                           \
    __builtin_amdgcn_sched_barrier(0);

#define G1_COMPUTE(KK, PAR, RD, DO_A)                                       \
    {                                                                       \
        bf16x8 af[4];                                                       \
        _Pragma("unroll") for (int fi = 0; fi < 4; fi++)                    \
            af[fi] = cvt8(pa[PAR][fi][0], pa[PAR][fi][1]);                  \
        if (DO_A) { G1_ISSUE_A((KK) + 2, PAR); }                            \
        _Pragma("unroll") for (int fjl = 0; fjl < 2; fjl++) {               \
            int fb = (wn * 2 + fjl) * 512 + lane * 4;                       \
            float4 u1 = *(const float4*)(RD + fb);                          \
            float4 v1 = *(const float4*)(RD + fb + 256);                    \
            float4 u3 = *(const float4*)(RD + 2048 + fb);                   \
            float4 v3 = *(const float4*)(RD + 2048 + fb + 256);             \
            bf16x8 b1 = cvt8(u1, v1), b3 = cvt8(u3, v3);                    \
            _Pragma("unroll") for (int fi = 0; fi < 4; fi++) {              \
                acc1[fi][fjl] = __builtin_amdgcn_mfma_f32_16x16x32_bf16(af[fi], b1, acc1[fi][fjl], 0, 0, 0); \
                acc3[fi][fjl] = __builtin_amdgcn_mfma_f32_16x16x32_bf16(af[fi], b3, acc3[fi][fjl], 0, 0, 0); \
            }                                                               \
        }                                                                   \
    }

#define G1_BODY(KK, PAR, WR, RD, N, DO_B, DO_A)                             \
    { if (DO_B) { G1_ISSUE_B((KK) + 2, WR); }                               \
      G1_SYNC(N)                                                            \
      G1_COMPUTE(KK, PAR, RD, DO_A) }

    // prologue: B0,A0,B1,A1  (order matters for vmcnt counting)
    G1_ISSUE_B(0, Bl0);
    G1_ISSUE_A(0, 0);
    G1_ISSUE_B(1, Bl1);
    G1_ISSUE_A(1, 1);

    // main: kk = 0..27 (rings static per position)
    for (int kb = 0; kb < 28; kb += 4) {
        G1_BODY(kb + 0, 0, Bl2, Bl0, 16, 1, 1)
        G1_BODY(kb + 1, 1, Bl3, Bl1, 16, 1, 1)
        G1_BODY(kb + 2, 0, Bl0, Bl2, 16, 1, 1)
        G1_BODY(kb + 3, 1, Bl1, Bl3, 16, 1, 1)
    }
    // peeled tail: kk = 28..31
    G1_BODY(28, 0, Bl2, Bl0, 16, 1, 1)
    G1_BODY(29, 1, Bl3, Bl1, 16, 1, 1)
    G1_BODY(30, 0, Bl0, Bl2, 12, 0, 0)
    G1_BODY(31, 1, Bl1, Bl3, 0, 0, 0)

    int rowBase = base[e];
#pragma unroll
    for (int fi = 0; fi < 4; fi++)
#pragma unroll
        for (int fjl = 0; fjl < 2; fjl++) {
            int ff = n0 + wn * 32 + fjl * 16 + l16;
#pragma unroll
            for (int r = 0; r < 4; r++) {
                int mm = m0 + wm * 64 + fi * 16 + quad * 4 + r;
                if (mm < cntE) {
                    float h1 = acc1[fi][fjl][r], h3 = acc3[fi][fjl][r];
                    float v = (h1 / (1.f + expf(-h1))) * h3;
                    inter[(size_t)(rowBase + mm) * F_DIM + ff] = (bf16_t)v;
                }
            }
        }
}

// ---------------- GEMM2: out = (inter @ w2^T) * wgt, scatter ----------------
// Block 128 rows x 64 cols, BK=32, 256 thr / 4 waves (2x2). Same pipeline,
// 8KB tiles, counted vmcnt 8/6/0. A (bf16 inter) direct depth-2.
__global__ __launch_bounds__(256, 2) void gemm2_k(
    const bf16_t* __restrict__ inter,
    const float* __restrict__ w2,
    const int* __restrict__ cnt, const int* __restrict__ base,
    const int* __restrict__ tok,
    const float* __restrict__ wgt, const int* __restrict__ slot,
    float* __restrict__ accOut)
{
    int mt = blockIdx.x >> 4;       // flat 128-row chunk across experts
    int nt = blockIdx.x & 15;       // 16 n-tiles of 64
    int e = 0, m0 = 0, found = 0, accb = 0;
#pragma unroll
    for (int ee = 0; ee < N_EXP; ee++) {
        int b = (cnt[ee] + 127) >> 7;
        if (!found && mt < accb + b) { e = ee; m0 = (mt - accb) << 7; found = 1; }
        accb += b;
    }
    if (!found) return;
    int cntE = cnt[e];
    int n0 = nt * 64;
    int tid = threadIdx.x;
    int lane = tid & 63, quad = lane >> 4, l16 = lane & 15;
    int wave = tid >> 6;
    int wm = wave >> 1, wn = wave & 1;
    int rowBase = base[e];

    __shared__ __align__(16) float Cl0[2048];
    __shared__ __align__(16) float Cl1[2048];
    __shared__ __align__(16) float Cl2[2048];
    __shared__ __align__(16) float Cl3[2048];

    const float* w2e = w2 + (size_t)e * H_DIM * F_DIM;

    // B DMA groups: g = wave*2+j; fj=g>>1, h=g&1.
    const float* srcB[2];
    int dstF[2];
#pragma unroll
    for (int j = 0; j < 2; j++) {
        int g = wave * 2 + j;
        int fj = g >> 1, h = g & 1;
        srcB[j] = w2e + (size_t)(n0 + fj * 16 + l16) * F_DIM + quad * 8 + h * 4;
        dstF[j] = fj * 512 + h * 256;
    }

    // A: per-lane direct rows into compacted bf16 inter
    int aoff[4];
#pragma unroll
    for (int fi = 0; fi < 4; fi++) {
        int rr = m0 + wm * 64 + fi * 16 + l16;
        if (rr >= cntE) rr = cntE - 1;
        aoff[fi] = (rowBase + rr) * F_DIM + quad * 8;
    }

    f32x4 acc[4][2];
#pragma unroll
    for (int fi = 0; fi < 4; fi++)
#pragma unroll
        for (int fj = 0; fj < 2; fj++) acc[fi][fj] = f32x4{0.f, 0.f, 0.f, 0.f};

    bf16x8 pa[2][4];

#define G2_ISSUE_B(T, WR)                                                   \
    { _Pragma("unroll") for (int j = 0; j < 2; j++)                         \
          gl16(srcB[j] + (T) * 32, WR + dstF[j]); }

#define G2_ISSUE_A(T, PAR)                                                  \
    { _Pragma("unroll") for (int fi = 0; fi < 4; fi++)                      \
          pa[PAR][fi] = *(const bf16x8*)(inter + aoff[fi] + (T) * 32); }

#define G2_COMPUTE(KK, PAR, RD, DO_A)                                       \
    {                                                                       \
        bf16x8 af[4];                                                       \
        _Pragma("unroll") for (int fi = 0; fi < 4; fi++) af[fi] = pa[PAR][fi]; \
        if (DO_A) { G2_ISSUE_A((KK) + 2, PAR); }                            \
        _Pragma("unroll") for (int fjl = 0; fjl < 2; fjl++) {               \
            int fb = (wn * 2 + fjl) * 512 + lane * 4;                       \
            float4 u = *(const float4*)(RD + fb);                           \
            float4 v = *(const float4*)(RD + fb + 256);                     \
            bf16x8 bfr = cvt8(u, v);                                        \
            _Pragma("unroll") for (int fi = 0; fi < 4; fi++)                \
                acc[fi][fjl] = __builtin_amdgcn_mfma_f32_16x16x32_bf16(af[fi], bfr, acc[fi][fjl], 0, 0, 0); \
        }                                                                   \
    }

#define G2_BODY(KK, PAR, WR, RD, N, DO_B, DO_A)                             \
    { if (DO_B) { G2_ISSUE_B((KK) + 2, WR); }                               \
      G1_SYNC(N)                                                            \
      G2_COMPUTE(KK, PAR, RD, DO_A) }

    G2_ISSUE_B(0, Cl0);
    G2_ISSUE_A(0, 0);
    G2_ISSUE_B(1, Cl1);
    G2_ISSUE_A(1, 1);

    for (int kb = 0; kb < 60; kb += 4) {
        G2_BODY(kb + 0, 0, Cl2, Cl0, 8, 1, 1)
        G2_BODY(kb + 1, 1, Cl3, Cl1, 8, 1, 1)
        G2_BODY(kb + 2, 0, Cl0, Cl2, 8, 1, 1)
        G2_BODY(kb + 3, 1, Cl1, Cl3, 8, 1, 1)
    }
    G2_BODY(60, 0, Cl2, Cl0, 8, 1, 1)
    G2_BODY(61, 1, Cl3, Cl1, 8, 1, 1)
    G2_BODY(62, 0, Cl0, Cl2, 6, 0, 0)
    G2_BODY(63, 1, Cl1, Cl3, 0, 0, 0)

#pragma unroll
    for (int fi = 0; fi < 4; fi++)
#pragma unroll
        for (int r = 0; r < 4; r++) {
            int mm = m0 + wm * 64 + fi * 16 + quad * 4 + r;
            if (mm < cntE) {
                int t = tok[e * T_TOK + mm];
                float wv = wgt[e * T_TOK + mm];
                int sl = slot[e * T_TOK + mm];
                float* dst = accOut + (size_t)sl * T_TOK * H_DIM + (size_t)t * H_DIM;
#pragma unroll
                for (int fjl = 0; fjl < 2; fjl++)
                    dst[n0 + wn * 32 + fjl * 16 + l16] = acc[fi][fjl][r] * wv;
            }
        }
}

// ---------------- combine ----------------
__global__ __launch_bounds__(256) void combine_k(const float* __restrict__ acc,
                                                 float* __restrict__ out)
{
    int i = blockIdx.x * 256 + threadIdx.x;
    const float4* a0 = (const float4*)acc;
    const float4* a1 = (const float4*)(acc + (size_t)T_TOK * H_DIM);
    float4 v0 = a0[i];
    float4 v1 = a1[i];
    float4 r;
    r.x = v0.x + v1.x; r.y = v0.y + v1.y; r.z = v0.z + v1.z; r.w = v0.w + v1.w;
    ((float4*)out)[i] = r;
}

extern "C" void kernel_launch(void* const* d_in, const int* in_sizes, int n_in,
                              void* d_out, int out_size, void* d_ws, size_t ws_size,
                              hipStream_t stream) {
    const float* x  = (const float*)d_in[0];
    const float* gw = (const float*)d_in[1];
    const float* w1 = (const float*)d_in[2];
    const float* w2 = (const float*)d_in[3];
    const float* w3 = (const float*)d_in[4];
    float* out = (float*)d_out;
    float* logits_out = out + (size_t)T_TOK * H_DIM;

    char* ws = (char*)d_ws;
    int*    cnt   = (int*)(ws + WS_CNT);
    int*    basep = (int*)(ws + WS_BASE);
    int*    tok   = (int*)(ws + WS_TOK);
    float*  wgt   = (float*)(ws + WS_WGT);
    int*    slot  = (int*)(ws + WS_SLOT);
    bf16_t* inter = (bf16_t*)(ws + WS_INTER);
    float*  accO  = (float*)(ws + WS_ACC);

    hipMemsetAsync(cnt, 0, 64, stream);
    router_k<<<T_TOK / 4, 256, 0, stream>>>(x, gw, logits_out, cnt, tok, wgt, slot);
    prefix_k<<<1, 64, 0, stream>>>(cnt, basep);
    gemm1_k<<<dim3(MT_MAX * 32), 256, 0, stream>>>(x, w1, w3, cnt, basep, tok, inter);
    gemm2_k<<<dim3(MT_MAX * 16), 256, 0, stream>>>(inter, w2, cnt, basep, tok, wgt, slot, accO);
    combine_k<<<(T_TOK * H_DIM / 4) / 256, 256, 0, stream>>>(accO, out);
}